// Round 1
// baseline (36921.045 us; speedup 1.0000x reference)
//
#include <hip/hip_runtime.h>
#include <hip/hip_bf16.h>
#include <math.h>

#define N_NODES 50000
#define BB 16
#define LL 128
#define DD 64
#define E_N 200000
#define ET_N 100000
#define TEMPF 12.0f

#define NLOG 240
#define CHUNK 209            // ceil(50000/240)
#define NCHUNK 14            // ceil(209/16)

__device__ __forceinline__ void ast(float* p, float v) {
  __hip_atomic_store(p, v, __ATOMIC_RELAXED, __HIP_MEMORY_SCOPE_AGENT);
}
__device__ __forceinline__ float ald(const float* p) {
  return __hip_atomic_load(p, __ATOMIC_RELAXED, __HIP_MEMORY_SCOPE_AGENT);
}
__device__ __forceinline__ unsigned ordf(float f) {
  unsigned u = __float_as_uint(f);
  return (u & 0x80000000u) ? ~u : (u | 0x80000000u);
}
__device__ void spin_ge(unsigned* c, unsigned target) {
  if (threadIdx.x == 0) {
    int it = 0;
    while (__hip_atomic_load(c, __ATOMIC_ACQUIRE, __HIP_MEMORY_SCOPE_AGENT) < target) {
      __builtin_amdgcn_s_sleep(2);
      if (++it > 4000000) break;   // catastrophic-bug escape, never hit if logic is right
    }
  }
  __syncthreads();
  __threadfence();
}

// ---------------- GNN phase ----------------

__global__ void k_node_enc(const float* __restrict__ nnf, const int* __restrict__ fid,
                           const float* __restrict__ femb, const float* __restrict__ W,
                           const float* __restrict__ bias, float* __restrict__ H) {
  __shared__ float sW[13 * 64];
  __shared__ float sF[80];
  __shared__ float sB[64];
  int tid = threadIdx.x;
  for (int i = tid; i < 13 * 64; i += 256) sW[i] = W[i];
  for (int i = tid; i < 80; i += 256) sF[i] = femb[i];
  if (tid < 64) sB[tid] = bias[tid];
  __syncthreads();
  int n = blockIdx.x * 4 + (tid >> 6);
  int d = tid & 63;
  if (n >= N_NODES) return;
  float acc = sB[d];
#pragma unroll
  for (int f = 0; f < 5; ++f) acc += nnf[n * 5 + f] * sW[f * 64 + d];
  int fl = fid[n];
#pragma unroll
  for (int j = 0; j < 8; ++j) acc += sF[fl * 8 + j] * sW[(5 + j) * 64 + d];
  H[n * 64 + d] = acc;
}

__global__ void k_edge_proj(const float* __restrict__ ea, const float* __restrict__ W1,
                            const float* __restrict__ b1, const float* __restrict__ W2,
                            const float* __restrict__ b2, float* __restrict__ Ee) {
  __shared__ float sW1[5 * 64];
  __shared__ float sB1[64];
  __shared__ float sW2[64 * 64];
  __shared__ float sB2[64];
  __shared__ float hid[4][64];
  int tid = threadIdx.x;
  for (int i = tid; i < 5 * 64; i += 256) sW1[i] = W1[i];
  for (int i = tid; i < 64 * 64; i += 256) sW2[i] = W2[i];
  if (tid < 64) { sB1[tid] = b1[tid]; sB2[tid] = b2[tid]; }
  __syncthreads();
  int w = tid >> 6, d = tid & 63;
  int e = blockIdx.x * 4 + w;
  float h = 0.f;
  if (e < E_N) {
    h = sB1[d];
#pragma unroll
    for (int f = 0; f < 5; ++f) h += ea[e * 5 + f] * sW1[f * 64 + d];
    h = fmaxf(h, 0.f);
  }
  hid[w][d] = h;
  __syncthreads();
  if (e >= E_N) return;
  float acc = sB2[d];
#pragma unroll 8
  for (int k = 0; k < 64; ++k) acc += hid[w][k] * sW2[k * 64 + d];
  Ee[e * 64 + d] = acc;
}

__global__ void k_gine_msg(const float* __restrict__ H, const float* __restrict__ Ee,
                           const int* __restrict__ ei, float* __restrict__ agg) {
  int tid = threadIdx.x;
  int e = blockIdx.x * 4 + (tid >> 6);
  int d = tid & 63;
  if (e >= E_N) return;
  int s = ei[e], t = ei[E_N + e];
  float m = fmaxf(H[s * 64 + d] + Ee[e * 64 + d], 0.f);
  atomicAdd(&agg[t * 64 + d], m);
}

__global__ __launch_bounds__(256) void k_gine_mlp(const float* __restrict__ H,
    const float* __restrict__ agg, const float* __restrict__ W1, const float* __restrict__ b1,
    const float* __restrict__ W2, const float* __restrict__ b2, float* __restrict__ Hout) {
  __shared__ float sW1[64 * 128];
  __shared__ float sW2[128 * 64];
  __shared__ float sB1[128];
  __shared__ float sB2[64];
  __shared__ float sx[2][64];
  __shared__ float sh[2][128];
  int tid = threadIdx.x;
  for (int i = tid; i < 64 * 128; i += 256) { sW1[i] = W1[i]; sW2[i] = W2[i]; }
  if (tid < 128) sB1[tid] = b1[tid];
  if (tid < 64) sB2[tid] = b2[tid];
  __syncthreads();
  int g = tid >> 7, j = tid & 127;
  const int ITER = 25;  // 1024 blocks * 2 nodes * 25 >= 50000
  for (int it = 0; it < ITER; ++it) {
    int n = (blockIdx.x + it * 1024) * 2 + g;
    if (j < 64 && n < N_NODES) sx[g][j] = H[n * 64 + j] + agg[n * 64 + j];
    __syncthreads();
    float hj = 0.f;
    if (n < N_NODES) {
      hj = sB1[j];
#pragma unroll 8
      for (int k = 0; k < 64; ++k) hj += sx[g][k] * sW1[k * 128 + j];
      hj = fmaxf(hj, 0.f);
    }
    sh[g][j] = hj;
    __syncthreads();
    if (j < 64 && n < N_NODES) {
      float acc = sB2[j];
#pragma unroll 8
      for (int k = 0; k < 128; ++k) acc += sh[g][k] * sW2[k * 64 + j];
      Hout[n * 64 + j] = fmaxf(acc, 0.f);
    }
    __syncthreads();
  }
}

__global__ void k_l2n(const float* __restrict__ H, float* __restrict__ Hn) {
  int tid = threadIdx.x;
  int n = blockIdx.x * 4 + (tid >> 6);
  int d = tid & 63;
  if (n >= N_NODES) return;
  float v = H[n * 64 + d];
  float ss = v * v;
#pragma unroll
  for (int o = 32; o > 0; o >>= 1) ss += __shfl_xor(ss, o, 64);
  float nr = fmaxf(sqrtf(ss), 1e-12f);
  Hn[n * 64 + d] = v / nr;
}

__global__ void k_traj_msg(const float* __restrict__ Hn, const int* __restrict__ tei,
                           const float* __restrict__ tw, float* __restrict__ agg) {
  int tid = threadIdx.x;
  int e = blockIdx.x * 4 + (tid >> 6);
  int d = tid & 63;
  if (e >= ET_N) return;
  int s = tei[e], t = tei[ET_N + e];
  atomicAdd(&agg[t * 64 + d], tw[e] * Hn[s * 64 + d]);
}

__global__ void k_traj_mlp(const float* __restrict__ Hn, const float* __restrict__ agg,
                           const float* __restrict__ Wt, const float* __restrict__ bt,
                           float* __restrict__ HR) {
  __shared__ float sW[64 * 64];
  __shared__ float sB[64];
  __shared__ float sx[4][64];
  int tid = threadIdx.x;
  for (int i = tid; i < 4096; i += 256) sW[i] = Wt[i];
  if (tid < 64) sB[tid] = bt[tid];
  __syncthreads();
  int w = tid >> 6, d = tid & 63;
  int n = blockIdx.x * 4 + w;
  if (n < N_NODES) sx[w][d] = Hn[n * 64 + d] + agg[n * 64 + d];
  __syncthreads();
  if (n >= N_NODES) return;
  float acc = sB[d];
#pragma unroll 8
  for (int k = 0; k < 64; ++k) acc += sx[w][k] * sW[k * 64 + d];
  acc = fmaxf(acc, 0.f);
  float ss = acc * acc;
#pragma unroll
  for (int o = 32; o > 0; o >>= 1) ss += __shfl_xor(ss, o, 64);
  float nr = fmaxf(sqrtf(ss), 1e-12f);
  HR[n * 64 + d] = acc / nr;
}

// ---------------- Encoder phase ----------------

// Per (b,t): gi_f = H_R[pred[b][t]] @ Wih_f + bih_f ; gi_b uses reversed gather.
__global__ __launch_bounds__(192) void k_gi(const int* __restrict__ pred,
    const int* __restrict__ lens, const float* __restrict__ HR,
    const float* __restrict__ Wf, const float* __restrict__ bf,
    const float* __restrict__ Wb, const float* __restrict__ bb,
    float* __restrict__ gif, float* __restrict__ gib) {
  __shared__ float xf[64];
  __shared__ float xb[64];
  int bid = blockIdx.x;
  int b = bid >> 7, t = bid & 127;
  int len = lens[b];
  int tid = threadIdx.x;
  bool act = (t < len);
  if (act && tid < 64) {
    int idx = pred[b * 128 + t];
    xf[tid] = HR[idx * 64 + tid];
    int idxb = pred[b * 128 + (len - 1 - t)];
    xb[tid] = HR[idxb * 64 + tid];
  }
  __syncthreads();
  if (!act) return;
  int j = tid;
  float a1 = bf[j], a2 = bb[j];
#pragma unroll 8
  for (int k = 0; k < 64; ++k) {
    a1 += xf[k] * Wf[k * 192 + j];
    a2 += xb[k] * Wb[k * 192 + j];
  }
  gif[(b * 128 + t) * 192 + j] = a1;
  gib[(b * 128 + t) * 192 + j] = a2;
}

// One block per (direction, b). Whh column lives in registers (64 VGPR/thread).
// Backward block writes its output un-reversed directly: out_b[b][len-1-t].
__global__ __launch_bounds__(192, 1) void k_gru(const float* __restrict__ gif,
    const float* __restrict__ gib, const float* __restrict__ Whf, const float* __restrict__ bhf,
    const float* __restrict__ Whb, const float* __restrict__ bhb, const int* __restrict__ lens,
    float* __restrict__ outf, float* __restrict__ outb) {
  __shared__ __align__(16) float h[64];
  __shared__ float s[192];
  __shared__ float ghn[64];
  int bid = blockIdx.x;
  int dir = bid >> 4, b = bid & 15;
  const float* gi = dir ? gib : gif;
  const float* Whh = dir ? Whb : Whf;
  const float* bhh = dir ? bhb : bhf;
  float* out = dir ? outb : outf;
  int len = lens[b];
  int j = threadIdx.x;
  float w[64];
#pragma unroll
  for (int k = 0; k < 64; ++k) w[k] = Whh[k * 192 + j];
  float bj = bhh[j];
  if (j < 64) h[j] = 0.f;
  __syncthreads();
  for (int t = 0; t < len; ++t) {
    float gij = gi[(b * 128 + t) * 192 + j];
    float gh = bj;
    const float4* h4 = (const float4*)h;
#pragma unroll
    for (int k4 = 0; k4 < 16; ++k4) {
      float4 hv = h4[k4];
      gh += hv.x * w[4 * k4] + hv.y * w[4 * k4 + 1] + hv.z * w[4 * k4 + 2] + hv.w * w[4 * k4 + 3];
    }
    if (j < 128) s[j] = gij + gh;
    else { s[j] = gij; ghn[j - 128] = gh; }
    __syncthreads();
    if (j < 64) {
      float r = 1.f / (1.f + expf(-s[j]));
      float z = 1.f / (1.f + expf(-s[64 + j]));
      float n = tanhf(s[128 + j] + r * ghn[j]);
      float hn = (1.f - z) * n + z * h[j];
      h[j] = hn;
      int tt = dir ? (len - 1 - t) : t;
      out[(b * 128 + tt) * 64 + j] = hn;
    }
    __syncthreads();
  }
  int total = (128 - len) * 64;
  for (int idx = j; idx < total; idx += 192) {
    int t2 = len + (idx >> 6), d = idx & 63;
    out[(b * 128 + t2) * 64 + d] = 0.f;
  }
}

__global__ void k_encout(const float* __restrict__ outf, const float* __restrict__ outb,
                         const float* __restrict__ Wep, const float* __restrict__ bep,
                         float* __restrict__ enc, float* __restrict__ encT) {
  __shared__ float cat[128];
  int bid = blockIdx.x;
  int b = bid >> 7, t = bid & 127;
  int d = threadIdx.x;  // 64 threads
  cat[d] = outf[bid * 64 + d];
  cat[64 + d] = outb[bid * 64 + d];
  __syncthreads();
  float acc = bep[d];
#pragma unroll 8
  for (int jj = 0; jj < 128; ++jj) acc += cat[jj] * Wep[jj * 64 + d];
  float ss = acc * acc;
#pragma unroll
  for (int o = 32; o > 0; o >>= 1) ss += __shfl_xor(ss, o, 64);
  float nr = fmaxf(sqrtf(ss), 1e-12f);
  float y = acc / nr;
  enc[bid * 64 + d] = y;
  encT[(b * 64 + d) * 128 + t] = y;
}

__global__ void k_encmean(const float* __restrict__ enc, const int* __restrict__ lens,
                          float* __restrict__ h0) {
  int tid = threadIdx.x;  // 1024
  int b = tid >> 6, d = tid & 63;
  int len = lens[b];
  float s = 0.f;
  for (int t = 0; t < len; ++t) s += enc[(b * 128 + t) * 64 + d];
  h0[b * 64 + d] = s / (float)len;
}

// ---------------- Decoder: persistent kernel, 128 steps ----------------
// blocks 0..15   : per-b GRU-elementwise + attention + z producer
// blocks 16..31  : gi = prev @ Wih_d (also logits worker)
// blocks 32..47  : gh = h    @ Whh_d (also logits worker)
// blocks 16..255 : logits + argmax over a fixed 209-node slice (L2-resident)
__global__ __launch_bounds__(256, 1) void k_decode(
    const float* __restrict__ HR, const float* __restrict__ enc, const float* __restrict__ encT,
    const float* __restrict__ Wih, const float* __restrict__ Whh,
    const float* __restrict__ bih, const float* __restrict__ bhh,
    const float* __restrict__ Wdo, const float* __restrict__ bdo,
    const int* __restrict__ lens, float* __restrict__ logits,
    unsigned* flags, unsigned long long* amax,
    float* h_slots, float* gi_s, float* gh_s, float* z_s) {
  __shared__ float sv[64];
  __shared__ float hS[64];
  __shared__ float aS[128];
  __shared__ float ctxS[64];
  __shared__ float red[2];
  __shared__ __align__(16) float zS[16][64];
  __shared__ unsigned long long bestS[256];

  unsigned* F_gi = flags + 0;
  unsigned* F_gh = flags + 1;
  unsigned* F_z  = flags + 2;
  unsigned* F_h  = flags + 3;
  unsigned* F_am = flags + 4;
  const int bid = blockIdx.x, tid = threadIdx.x;

  if (bid < 16) {
    const int b = bid, len = lens[b];
    for (int t = 0; t < 128; ++t) {
      spin_ge(F_gi, 16u * (t + 1));
      spin_ge(F_gh, 16u * (t + 1));
      if (tid < 64) {
        const int d = tid;
        const float* gi = gi_s + (t * 16 + b) * 192;
        const float* gh = gh_s + (t * 16 + b) * 192;
        float gir = ald(gi + d), giz = ald(gi + 64 + d), gin = ald(gi + 128 + d);
        float ghr = ald(gh + d), ghz = ald(gh + 64 + d), ghn2 = ald(gh + 128 + d);
        float hold = ald(&h_slots[(t * 16 + b) * 64 + d]);
        float r = 1.f / (1.f + expf(-(gir + ghr)));
        float zz = 1.f / (1.f + expf(-(giz + ghz)));
        float nn = tanhf(gin + r * ghn2);
        float hn = (1.f - zz) * nn + zz * hold;
        ast(&h_slots[((t + 1) * 16 + b) * 64 + d], hn);
        hS[d] = hn;
      }
      __syncthreads();
      __threadfence();
      if (tid == 0) __hip_atomic_fetch_add(F_h, 1u, __ATOMIC_RELEASE, __HIP_MEMORY_SCOPE_AGENT);
      // scores over L=128 (2 waves), masked to l < len
      float sc = -1e9f, p = 0.f;
      if (tid < 128 && tid < len) {
        float a = 0.f;
        const float* eT = encT + b * 8192 + tid;
#pragma unroll 8
        for (int d2 = 0; d2 < 64; ++d2) a += hS[d2] * eT[d2 * 128];
        sc = a;
      }
      float m = sc;
#pragma unroll
      for (int o = 32; o > 0; o >>= 1) m = fmaxf(m, __shfl_xor(m, o, 64));
      if (tid < 128 && (tid & 63) == 0) red[tid >> 6] = m;
      __syncthreads();
      m = fmaxf(red[0], red[1]);
      if (tid < 128) p = expf(sc - m);
      float sm = p;
#pragma unroll
      for (int o = 32; o > 0; o >>= 1) sm += __shfl_xor(sm, o, 64);
      __syncthreads();
      if (tid < 128 && (tid & 63) == 0) red[tid >> 6] = sm;
      __syncthreads();
      float tot = red[0] + red[1];
      if (tid < 128) aS[tid] = p / tot;
      __syncthreads();
      if (tid < 64) {
        float cx = 0.f;
        const float* eb = enc + b * 8192 + tid;
#pragma unroll 8
        for (int l = 0; l < 128; ++l) cx += aS[l] * eb[l * 64];
        ctxS[tid] = cx;
      }
      __syncthreads();
      if (tid < 64) {
        const int d = tid;
        float acc = bdo[d];
#pragma unroll 8
        for (int jj = 0; jj < 64; ++jj) acc += hS[jj] * Wdo[jj * 64 + d];
#pragma unroll 8
        for (int jj = 0; jj < 64; ++jj) acc += ctxS[jj] * Wdo[(64 + jj) * 64 + d];
        float ss = acc * acc;
#pragma unroll
        for (int o = 32; o > 0; o >>= 1) ss += __shfl_xor(ss, o, 64);
        float nr = fmaxf(sqrtf(ss), 1e-12f);
        ast(&z_s[(t * 16 + b) * 64 + d], acc / nr);
      }
      __syncthreads();
      __threadfence();
      if (tid == 0) __hip_atomic_fetch_add(F_z, 1u, __ATOMIC_RELEASE, __HIP_MEMORY_SCOPE_AGENT);
    }
    return;
  }

  const int lb = bid - 16;
  const int n0 = lb * CHUNK;
  const int n1 = min(n0 + CHUNK, N_NODES);
  const bool isGi = (bid < 32);
  const bool isGh = (bid >= 32 && bid < 48);
  const int pb = isGi ? (bid - 16) : (bid - 32);

  for (int t = 0; t < 128; ++t) {
    if (isGi) {
      if (t > 0) spin_ge(F_am, (unsigned)NLOG * (unsigned)t);
      if (tid < 64) {
        float pv = 0.f;
        if (t > 0) {
          unsigned long long pk = __hip_atomic_load(&amax[(t - 1) * 16 + pb],
                                                    __ATOMIC_RELAXED, __HIP_MEMORY_SCOPE_AGENT);
          unsigned nprev = 0xFFFFFFFFu - (unsigned)(pk & 0xFFFFFFFFull);
          nprev = nprev < (unsigned)N_NODES ? nprev : (unsigned)(N_NODES - 1);
          pv = HR[nprev * 64 + tid];
        }
        sv[tid] = pv;
      }
      __syncthreads();
      if (tid < 192) {
        float acc = bih[tid];
#pragma unroll
        for (int k = 0; k < 64; ++k) acc += sv[k] * Wih[k * 192 + tid];
        ast(&gi_s[(t * 16 + pb) * 192 + tid], acc);
      }
      __syncthreads();
      __threadfence();
      if (tid == 0) __hip_atomic_fetch_add(F_gi, 1u, __ATOMIC_RELEASE, __HIP_MEMORY_SCOPE_AGENT);
    } else if (isGh) {
      spin_ge(F_h, 16u * (unsigned)t);
      if (tid < 64) sv[tid] = ald(&h_slots[(t * 16 + pb) * 64 + tid]);
      __syncthreads();
      if (tid < 192) {
        float acc = bhh[tid];
#pragma unroll
        for (int k = 0; k < 64; ++k) acc += sv[k] * Whh[k * 192 + tid];
        ast(&gh_s[(t * 16 + pb) * 192 + tid], acc);
      }
      __syncthreads();
      __threadfence();
      if (tid == 0) __hip_atomic_fetch_add(F_gh, 1u, __ATOMIC_RELEASE, __HIP_MEMORY_SCOPE_AGENT);
    }
    // -------- logits + argmax for this block's node slice --------
    spin_ge(F_z, 16u * (t + 1));
    for (int idx = tid; idx < 1024; idx += 256) zS[idx >> 6][idx & 63] = ald(&z_s[t * 1024 + idx]);
    __syncthreads();
    const int b2 = tid >> 4, i0 = tid & 15;
    float4 zr[16];
    {
      const float4* zp4 = (const float4*)(&zS[b2][0]);
#pragma unroll
      for (int q = 0; q < 16; ++q) zr[q] = zp4[q];
    }
    unsigned long long best = 0ull;
    float* lrow = logits + (size_t)b2 * 6400000u + (size_t)t * 50000u;
    for (int c = 0; c < NCHUNK; ++c) {
      int n = n0 + c * 16 + i0;
      if (n < n1) {
        const float4* hp = (const float4*)(HR + n * 64);
        float acc = 0.f;
#pragma unroll
        for (int q = 0; q < 16; ++q) {
          float4 hv = hp[q];
          float4 zv = zr[q];
          acc += hv.x * zv.x + hv.y * zv.y + hv.z * zv.z + hv.w * zv.w;
        }
        float lg = TEMPF * acc;
        __builtin_nontemporal_store(lg, &lrow[n]);
        unsigned long long key = ((unsigned long long)ordf(lg) << 32)
                               | (unsigned long long)(0xFFFFFFFFu - (unsigned)n);
        best = (key > best) ? key : best;
      }
    }
    bestS[tid] = best;
    __syncthreads();
    if (tid < 16) {
      unsigned long long mm = 0ull;
#pragma unroll
      for (int i = 0; i < 16; ++i) mm = max(mm, bestS[tid * 16 + i]);
      unsigned long long cur = __hip_atomic_load(&amax[t * 16 + tid],
                                                 __ATOMIC_RELAXED, __HIP_MEMORY_SCOPE_AGENT);
      if (mm > cur) atomicMax(&amax[t * 16 + tid], mm);
    }
    __syncthreads();
    __threadfence();
    if (tid == 0) __hip_atomic_fetch_add(F_am, 1u, __ATOMIC_RELEASE, __HIP_MEMORY_SCOPE_AGENT);
    __syncthreads();
  }
}

// ---------------- launch ----------------

extern "C" void kernel_launch(void* const* d_in, const int* in_sizes, int n_in,
                              void* d_out, int out_size, void* d_ws, size_t ws_size,
                              hipStream_t stream) {
  const int* pred = (const int*)d_in[0];
  const int* lens = (const int*)d_in[1];
  const float* nnf = (const float*)d_in[2];
  const int* fid = (const int*)d_in[3];
  const int* ei = (const int*)d_in[4];
  const float* ea = (const float*)d_in[5];
  const int* tei = (const int*)d_in[6];
  const float* tw = (const float*)d_in[7];
  const float* femb = (const float*)d_in[8];
  const float* W_ne = (const float*)d_in[9];  const float* b_ne = (const float*)d_in[10];
  const float* W_e1 = (const float*)d_in[11]; const float* b_e1 = (const float*)d_in[12];
  const float* W_e2 = (const float*)d_in[13]; const float* b_e2 = (const float*)d_in[14];
  const float* g1W1 = (const float*)d_in[15]; const float* g1b1 = (const float*)d_in[16];
  const float* g1W2 = (const float*)d_in[17]; const float* g1b2 = (const float*)d_in[18];
  const float* g2W1 = (const float*)d_in[19]; const float* g2b1 = (const float*)d_in[20];
  const float* g2W2 = (const float*)d_in[21]; const float* g2b2 = (const float*)d_in[22];
  const float* W_t = (const float*)d_in[23];  const float* b_t = (const float*)d_in[24];
  const float* Wihf = (const float*)d_in[25]; const float* Whhf = (const float*)d_in[26];
  const float* bihf = (const float*)d_in[27]; const float* bhhf = (const float*)d_in[28];
  const float* Wihb = (const float*)d_in[29]; const float* Whhb = (const float*)d_in[30];
  const float* bihb = (const float*)d_in[31]; const float* bhhb = (const float*)d_in[32];
  const float* W_ep = (const float*)d_in[33]; const float* b_ep = (const float*)d_in[34];
  const float* Wihd = (const float*)d_in[35]; const float* Whhd = (const float*)d_in[36];
  const float* bihd = (const float*)d_in[37]; const float* bhhd = (const float*)d_in[38];
  const float* W_do = (const float*)d_in[39]; const float* b_do = (const float*)d_in[40];

  float* out = (float*)d_out;
  float* logits = out;
  float* HR = out + 102400000;  // second output

  // large scratch lives in the (not-yet-written) logits region
  float* Ee    = out + 0;
  float* H_a   = out + 12800000;
  float* H_b   = out + 16000000;
  float* agg   = out + 19200000;
  float* HRt   = out + 22400000;
  float* gi_f  = out + 25600000;
  float* gi_b  = out + 26000000;
  float* out_f = out + 26400000;
  float* out_b = out + 26600000;

  // decode-live scratch in d_ws (~5.1 MB)
  char* w8 = (char*)d_ws;
  unsigned* flags = (unsigned*)w8;                                   // 256 B
  unsigned long long* amax = (unsigned long long*)(w8 + 256);        // 16 KB
  float* h_slots = (float*)(w8 + 16896);                             // 129*16*64*4
  float* gi_s = (float*)(w8 + 16896 + 528384);                       // 128*16*192*4
  float* gh_s = (float*)(w8 + 16896 + 528384 + 1572864);
  float* z_s  = (float*)(w8 + 16896 + 528384 + 2 * 1572864);         // 128*16*64*4
  float* enc  = (float*)(w8 + 16896 + 528384 + 2 * 1572864 + 524288);
  float* encT = (float*)(w8 + 16896 + 528384 + 2 * 1572864 + 2 * 524288);

  hipMemsetAsync(flags, 0, 16896, stream);  // flags + amax slots

  k_node_enc<<<12500, 256, 0, stream>>>(nnf, fid, femb, W_ne, b_ne, H_a);
  k_edge_proj<<<50000, 256, 0, stream>>>(ea, W_e1, b_e1, W_e2, b_e2, Ee);

  hipMemsetAsync(agg, 0, (size_t)N_NODES * 64 * 4, stream);
  k_gine_msg<<<50000, 256, 0, stream>>>(H_a, Ee, ei, agg);
  k_gine_mlp<<<1024, 256, 0, stream>>>(H_a, agg, g1W1, g1b1, g1W2, g1b2, H_b);

  hipMemsetAsync(agg, 0, (size_t)N_NODES * 64 * 4, stream);
  k_gine_msg<<<50000, 256, 0, stream>>>(H_b, Ee, ei, agg);
  k_gine_mlp<<<1024, 256, 0, stream>>>(H_b, agg, g2W1, g2b1, g2W2, g2b2, H_a);

  k_l2n<<<12500, 256, 0, stream>>>(H_a, HRt);

  hipMemsetAsync(agg, 0, (size_t)N_NODES * 64 * 4, stream);
  k_traj_msg<<<25000, 256, 0, stream>>>(HRt, tei, tw, agg);
  k_traj_mlp<<<12500, 256, 0, stream>>>(HRt, agg, W_t, b_t, HR);

  k_gi<<<2048, 192, 0, stream>>>(pred, lens, HR, Wihf, bihf, Wihb, bihb, gi_f, gi_b);
  k_gru<<<32, 192, 0, stream>>>(gi_f, gi_b, Whhf, bhhf, Whhb, bhhb, lens, out_f, out_b);
  k_encout<<<2048, 64, 0, stream>>>(out_f, out_b, W_ep, b_ep, enc, encT);
  k_encmean<<<1, 1024, 0, stream>>>(enc, lens, h_slots);

  k_decode<<<256, 256, 0, stream>>>(HR, enc, encT, Wihd, Whhd, bihd, bhhd, W_do, b_do,
                                    lens, logits, flags, amax, h_slots, gi_s, gh_s, z_s);
}

// Round 4
// 4381.845 us; speedup vs baseline: 8.4259x; 8.4259x over previous
//
#include <hip/hip_runtime.h>
#include <hip/hip_bf16.h>
#include <math.h>

#define N_NODES 50000
#define BB 16
#define LL 128
#define DD 64
#define E_N 200000
#define ET_N 100000
#define TEMPF 12.0f

typedef unsigned long long ull;

__device__ __forceinline__ unsigned ordf(float f) {
  unsigned u = __float_as_uint(f);
  return (u & 0x80000000u) ? ~u : (u | 0x80000000u);
}

// ---------------- GNN phase (unchanged, harness-verified) ----------------

__global__ void k_node_enc(const float* __restrict__ nnf, const int* __restrict__ fid,
                           const float* __restrict__ femb, const float* __restrict__ W,
                           const float* __restrict__ bias, float* __restrict__ H) {
  __shared__ float sW[13 * 64];
  __shared__ float sF[80];
  __shared__ float sB[64];
  int tid = threadIdx.x;
  for (int i = tid; i < 13 * 64; i += 256) sW[i] = W[i];
  for (int i = tid; i < 80; i += 256) sF[i] = femb[i];
  if (tid < 64) sB[tid] = bias[tid];
  __syncthreads();
  int n = blockIdx.x * 4 + (tid >> 6);
  int d = tid & 63;
  if (n >= N_NODES) return;
  float acc = sB[d];
#pragma unroll
  for (int f = 0; f < 5; ++f) acc += nnf[n * 5 + f] * sW[f * 64 + d];
  int fl = fid[n];
#pragma unroll
  for (int j = 0; j < 8; ++j) acc += sF[fl * 8 + j] * sW[(5 + j) * 64 + d];
  H[n * 64 + d] = acc;
}

__global__ void k_edge_proj(const float* __restrict__ ea, const float* __restrict__ W1,
                            const float* __restrict__ b1, const float* __restrict__ W2,
                            const float* __restrict__ b2, float* __restrict__ Ee) {
  __shared__ float sW1[5 * 64];
  __shared__ float sB1[64];
  __shared__ float sW2[64 * 64];
  __shared__ float sB2[64];
  __shared__ float hid[4][64];
  int tid = threadIdx.x;
  for (int i = tid; i < 5 * 64; i += 256) sW1[i] = W1[i];
  for (int i = tid; i < 64 * 64; i += 256) sW2[i] = W2[i];
  if (tid < 64) { sB1[tid] = b1[tid]; sB2[tid] = b2[tid]; }
  __syncthreads();
  int w = tid >> 6, d = tid & 63;
  int e = blockIdx.x * 4 + w;
  float h = 0.f;
  if (e < E_N) {
    h = sB1[d];
#pragma unroll
    for (int f = 0; f < 5; ++f) h += ea[e * 5 + f] * sW1[f * 64 + d];
    h = fmaxf(h, 0.f);
  }
  hid[w][d] = h;
  __syncthreads();
  if (e >= E_N) return;
  float acc = sB2[d];
#pragma unroll 8
  for (int k = 0; k < 64; ++k) acc += hid[w][k] * sW2[k * 64 + d];
  Ee[e * 64 + d] = acc;
}

__global__ void k_gine_msg(const float* __restrict__ H, const float* __restrict__ Ee,
                           const int* __restrict__ ei, float* __restrict__ agg) {
  int tid = threadIdx.x;
  int e = blockIdx.x * 4 + (tid >> 6);
  int d = tid & 63;
  if (e >= E_N) return;
  int s = ei[e], t = ei[E_N + e];
  float m = fmaxf(H[s * 64 + d] + Ee[e * 64 + d], 0.f);
  atomicAdd(&agg[t * 64 + d], m);
}

__global__ __launch_bounds__(256) void k_gine_mlp(const float* __restrict__ H,
    const float* __restrict__ agg, const float* __restrict__ W1, const float* __restrict__ b1,
    const float* __restrict__ W2, const float* __restrict__ b2, float* __restrict__ Hout) {
  __shared__ float sW1[64 * 128];
  __shared__ float sW2[128 * 64];
  __shared__ float sB1[128];
  __shared__ float sB2[64];
  __shared__ float sx[2][64];
  __shared__ float sh[2][128];
  int tid = threadIdx.x;
  for (int i = tid; i < 64 * 128; i += 256) { sW1[i] = W1[i]; sW2[i] = W2[i]; }
  if (tid < 128) sB1[tid] = b1[tid];
  if (tid < 64) sB2[tid] = b2[tid];
  __syncthreads();
  int g = tid >> 7, j = tid & 127;
  const int ITER = 25;
  for (int it = 0; it < ITER; ++it) {
    int n = (blockIdx.x + it * 1024) * 2 + g;
    if (j < 64 && n < N_NODES) sx[g][j] = H[n * 64 + j] + agg[n * 64 + j];
    __syncthreads();
    float hj = 0.f;
    if (n < N_NODES) {
      hj = sB1[j];
#pragma unroll 8
      for (int k = 0; k < 64; ++k) hj += sx[g][k] * sW1[k * 128 + j];
      hj = fmaxf(hj, 0.f);
    }
    sh[g][j] = hj;
    __syncthreads();
    if (j < 64 && n < N_NODES) {
      float acc = sB2[j];
#pragma unroll 8
      for (int k = 0; k < 128; ++k) acc += sh[g][k] * sW2[k * 64 + j];
      Hout[n * 64 + j] = fmaxf(acc, 0.f);
    }
    __syncthreads();
  }
}

__global__ void k_l2n(const float* __restrict__ H, float* __restrict__ Hn) {
  int tid = threadIdx.x;
  int n = blockIdx.x * 4 + (tid >> 6);
  int d = tid & 63;
  if (n >= N_NODES) return;
  float v = H[n * 64 + d];
  float ss = v * v;
#pragma unroll
  for (int o = 32; o > 0; o >>= 1) ss += __shfl_xor(ss, o, 64);
  float nr = fmaxf(sqrtf(ss), 1e-12f);
  Hn[n * 64 + d] = v / nr;
}

__global__ void k_traj_msg(const float* __restrict__ Hn, const int* __restrict__ tei,
                           const float* __restrict__ tw, float* __restrict__ agg) {
  int tid = threadIdx.x;
  int e = blockIdx.x * 4 + (tid >> 6);
  int d = tid & 63;
  if (e >= ET_N) return;
  int s = tei[e], t = tei[ET_N + e];
  atomicAdd(&agg[t * 64 + d], tw[e] * Hn[s * 64 + d]);
}

__global__ void k_traj_mlp(const float* __restrict__ Hn, const float* __restrict__ agg,
                           const float* __restrict__ Wt, const float* __restrict__ bt,
                           float* __restrict__ HR) {
  __shared__ float sW[64 * 64];
  __shared__ float sB[64];
  __shared__ float sx[4][64];
  int tid = threadIdx.x;
  for (int i = tid; i < 4096; i += 256) sW[i] = Wt[i];
  if (tid < 64) sB[tid] = bt[tid];
  __syncthreads();
  int w = tid >> 6, d = tid & 63;
  int n = blockIdx.x * 4 + w;
  if (n < N_NODES) sx[w][d] = Hn[n * 64 + d] + agg[n * 64 + d];
  __syncthreads();
  if (n >= N_NODES) return;
  float acc = sB[d];
#pragma unroll 8
  for (int k = 0; k < 64; ++k) acc += sx[w][k] * sW[k * 64 + d];
  acc = fmaxf(acc, 0.f);
  float ss = acc * acc;
#pragma unroll
  for (int o = 32; o > 0; o >>= 1) ss += __shfl_xor(ss, o, 64);
  float nr = fmaxf(sqrtf(ss), 1e-12f);
  HR[n * 64 + d] = acc / nr;
}

// ---------------- Encoder phase (unchanged) ----------------

__global__ __launch_bounds__(192) void k_gi(const int* __restrict__ pred,
    const int* __restrict__ lens, const float* __restrict__ HR,
    const float* __restrict__ Wf, const float* __restrict__ bf,
    const float* __restrict__ Wb, const float* __restrict__ bb,
    float* __restrict__ gif, float* __restrict__ gib) {
  __shared__ float xf[64];
  __shared__ float xb[64];
  int bid = blockIdx.x;
  int b = bid >> 7, t = bid & 127;
  int len = lens[b];
  int tid = threadIdx.x;
  bool act = (t < len);
  if (act && tid < 64) {
    int idx = pred[b * 128 + t];
    xf[tid] = HR[idx * 64 + tid];
    int idxb = pred[b * 128 + (len - 1 - t)];
    xb[tid] = HR[idxb * 64 + tid];
  }
  __syncthreads();
  if (!act) return;
  int j = tid;
  float a1 = bf[j], a2 = bb[j];
#pragma unroll 8
  for (int k = 0; k < 64; ++k) {
    a1 += xf[k] * Wf[k * 192 + j];
    a2 += xb[k] * Wb[k * 192 + j];
  }
  gif[(b * 128 + t) * 192 + j] = a1;
  gib[(b * 128 + t) * 192 + j] = a2;
}

__global__ __launch_bounds__(192, 1) void k_gru(const float* __restrict__ gif,
    const float* __restrict__ gib, const float* __restrict__ Whf, const float* __restrict__ bhf,
    const float* __restrict__ Whb, const float* __restrict__ bhb, const int* __restrict__ lens,
    float* __restrict__ outf, float* __restrict__ outb) {
  __shared__ __align__(16) float h[64];
  __shared__ float s[192];
  __shared__ float ghn[64];
  int bid = blockIdx.x;
  int dir = bid >> 4, b = bid & 15;
  const float* gi = dir ? gib : gif;
  const float* Whh = dir ? Whb : Whf;
  const float* bhh = dir ? bhb : bhf;
  float* out = dir ? outb : outf;
  int len = lens[b];
  int j = threadIdx.x;
  float w[64];
#pragma unroll
  for (int k = 0; k < 64; ++k) w[k] = Whh[k * 192 + j];
  float bj = bhh[j];
  if (j < 64) h[j] = 0.f;
  __syncthreads();
  for (int t = 0; t < len; ++t) {
    float gij = gi[(b * 128 + t) * 192 + j];
    float gh = bj;
    const float4* h4 = (const float4*)h;
#pragma unroll
    for (int k4 = 0; k4 < 16; ++k4) {
      float4 hv = h4[k4];
      gh += hv.x * w[4 * k4] + hv.y * w[4 * k4 + 1] + hv.z * w[4 * k4 + 2] + hv.w * w[4 * k4 + 3];
    }
    if (j < 128) s[j] = gij + gh;
    else { s[j] = gij; ghn[j - 128] = gh; }
    __syncthreads();
    if (j < 64) {
      float r = 1.f / (1.f + expf(-s[j]));
      float z = 1.f / (1.f + expf(-s[64 + j]));
      float n = tanhf(s[128 + j] + r * ghn[j]);
      float hn = (1.f - z) * n + z * h[j];
      h[j] = hn;
      int tt = dir ? (len - 1 - t) : t;
      out[(b * 128 + tt) * 64 + j] = hn;
    }
    __syncthreads();
  }
  int total = (128 - len) * 64;
  for (int idx = j; idx < total; idx += 192) {
    int t2 = len + (idx >> 6), d = idx & 63;
    out[(b * 128 + t2) * 64 + d] = 0.f;
  }
}

__global__ void k_encout(const float* __restrict__ outf, const float* __restrict__ outb,
                         const float* __restrict__ Wep, const float* __restrict__ bep,
                         float* __restrict__ enc, float* __restrict__ encT) {
  __shared__ float cat[128];
  int bid = blockIdx.x;
  int b = bid >> 7, t = bid & 127;
  int d = threadIdx.x;  // 64 threads
  cat[d] = outf[bid * 64 + d];
  cat[64 + d] = outb[bid * 64 + d];
  __syncthreads();
  float acc = bep[d];
#pragma unroll 8
  for (int jj = 0; jj < 128; ++jj) acc += cat[jj] * Wep[jj * 64 + d];
  float ss = acc * acc;
#pragma unroll
  for (int o = 32; o > 0; o >>= 1) ss += __shfl_xor(ss, o, 64);
  float nr = fmaxf(sqrtf(ss), 1e-12f);
  float y = acc / nr;
  enc[bid * 64 + d] = y;
  encT[(b * 64 + d) * 128 + t] = y;
}

__global__ void k_encmean(const float* __restrict__ enc, const int* __restrict__ lens,
                          float* __restrict__ h_g) {
  int tid = threadIdx.x;  // 1024
  int b = tid >> 6, d = tid & 63;
  int len = lens[b];
  float s = 0.f;
  for (int t = 0; t < len; ++t) s += enc[(b * 128 + t) * 64 + d];
  h_g[b * 64 + d] = s / (float)len;
}

// ---------------- Decoder v3: stream-ordered, 2 launches per step ----------------
// No inter-block sync anywhere: correctness ordered purely by stream. Hang-proof.
// k_dec_a (16 blocks, one per b): reduce prev step's 256 argmax partials (plain
//   loads), gather HR[winner], GRU update, attention, z -> z_g, h_g.
// k_dec_b (196 blocks x 256 thr): block covers 256 nodes for ALL 16 b (HR row
//   read once per step), writes logits + per-(b,block) argmax partial to slots.

__global__ __launch_bounds__(192) void k_dec_a(const float* __restrict__ HR,
    const float* __restrict__ enc, const float* __restrict__ encT,
    const float* __restrict__ Wih, const float* __restrict__ Whh,
    const float* __restrict__ bih, const float* __restrict__ bhh,
    const float* __restrict__ Wdo, const float* __restrict__ bdo,
    const int* __restrict__ lens, float* __restrict__ h_g, float* __restrict__ z_g,
    const ull* __restrict__ slots, int t) {
  __shared__ float sv[64];
  __shared__ float hP[64];
  __shared__ float sS[192];
  __shared__ float sGhn[64];
  __shared__ float aS[128];
  __shared__ float ctxS[64];
  __shared__ float red[2];
  __shared__ int widxS;
  const int b = blockIdx.x, tid = threadIdx.x;
  const int len = lens[b];

  if (t > 0 && tid < 64) {
    const ull* sb = slots + (size_t)b * 256;
    ull k0 = sb[tid], k1 = sb[tid + 64], k2 = sb[tid + 128], k3 = sb[tid + 192];
    ull k = k0 > k1 ? k0 : k1;
    ull k23 = k2 > k3 ? k2 : k3;
    k = k > k23 ? k : k23;
#pragma unroll
    for (int o = 32; o > 0; o >>= 1) {
      ull other = __shfl_xor(k, o, 64);
      k = k > other ? k : other;
    }
    if (tid == 0) {
      unsigned w = 0xFFFFFFFFu - (unsigned)(k & 0xFFFFFFFFull);
      widxS = (int)(w < (unsigned)N_NODES ? w : (unsigned)(N_NODES - 1));
    }
  }
  if (tid < 64) hP[tid] = h_g[b * 64 + tid];
  __syncthreads();
  if (tid < 64) sv[tid] = (t > 0) ? HR[(size_t)widxS * 64 + tid] : 0.f;
  __syncthreads();
  // gi = x @ Wih + bih ; gh = h @ Whh + bhh   (192 threads, one output each)
  {
    float gi = bih[tid], gh = bhh[tid];
#pragma unroll 8
    for (int k = 0; k < 64; ++k) {
      gi += sv[k] * Wih[k * 192 + tid];
      gh += hP[k] * Whh[k * 192 + tid];
    }
    if (tid < 128) sS[tid] = gi + gh;
    else { sS[tid] = gi; sGhn[tid - 128] = gh; }
  }
  __syncthreads();
  // GRU elementwise
  if (tid < 64) {
    float r = 1.f / (1.f + expf(-sS[tid]));
    float zz = 1.f / (1.f + expf(-sS[64 + tid]));
    float nn = tanhf(sS[128 + tid] + r * sGhn[tid]);
    float hn = (1.f - zz) * nn + zz * hP[tid];
    hP[tid] = hn;
    h_g[b * 64 + tid] = hn;
  }
  __syncthreads();
  // attention scores + softmax over L=128 (masked to l < len)
  float sc = -1e9f, p = 0.f;
  if (tid < 128 && tid < len) {
    float a = 0.f;
    const float* eT = encT + b * 8192 + tid;
#pragma unroll 8
    for (int d2 = 0; d2 < 64; ++d2) a += hP[d2] * eT[d2 * 128];
    sc = a;
  }
  float m = sc;
#pragma unroll
  for (int o = 32; o > 0; o >>= 1) m = fmaxf(m, __shfl_xor(m, o, 64));
  if (tid < 128 && (tid & 63) == 0) red[tid >> 6] = m;
  __syncthreads();
  m = fmaxf(red[0], red[1]);
  if (tid < 128) p = expf(sc - m);
  float sm = p;
#pragma unroll
  for (int o = 32; o > 0; o >>= 1) sm += __shfl_xor(sm, o, 64);
  __syncthreads();
  if (tid < 128 && (tid & 63) == 0) red[tid >> 6] = sm;
  __syncthreads();
  float tot = red[0] + red[1];
  if (tid < 128) aS[tid] = p / tot;
  __syncthreads();
  // context
  if (tid < 64) {
    float cx = 0.f;
    const float* eb = enc + b * 8192 + tid;
#pragma unroll 8
    for (int l = 0; l < 128; ++l) cx += aS[l] * eb[l * 64];
    ctxS[tid] = cx;
  }
  __syncthreads();
  // z = l2n([h, ctx] @ Wdo + bdo)
  if (tid < 64) {
    float acc = bdo[tid];
#pragma unroll 8
    for (int jj = 0; jj < 64; ++jj) acc += hP[jj] * Wdo[jj * 64 + tid];
#pragma unroll 8
    for (int jj = 0; jj < 64; ++jj) acc += ctxS[jj] * Wdo[(64 + jj) * 64 + tid];
    float ss = acc * acc;
#pragma unroll
    for (int o = 32; o > 0; o >>= 1) ss += __shfl_xor(ss, o, 64);
    float nr = fmaxf(sqrtf(ss), 1e-12f);
    z_g[b * 64 + tid] = acc / nr;
  }
}

__global__ __launch_bounds__(256) void k_dec_b(const float* __restrict__ HR,
    const float* __restrict__ z_g, float* __restrict__ logits,
    ull* __restrict__ slots, int t) {
  __shared__ __align__(16) float zS[16][64];
  __shared__ ull bw[4][16];
  const int bid = blockIdx.x, tid = threadIdx.x;
  for (int i = tid; i < 1024; i += 256) zS[i >> 6][i & 63] = z_g[i];
  __syncthreads();
  const int n = bid * 256 + tid;
  ull kk[16];
  const bool valid = n < N_NODES;
  if (valid) {
    const float4* hp = (const float4*)(HR + (size_t)n * 64);
    float4 hv[16];
#pragma unroll
    for (int q = 0; q < 16; ++q) hv[q] = hp[q];
    float* lbase = logits + (size_t)t * 50000u + n;
#pragma unroll
    for (int b = 0; b < 16; ++b) {
      const float4* zp = (const float4*)(&zS[b][0]);
      float acc = 0.f;
#pragma unroll
      for (int q = 0; q < 16; ++q) {
        float4 zv = zp[q];
        acc += hv[q].x * zv.x + hv[q].y * zv.y + hv[q].z * zv.z + hv[q].w * zv.w;
      }
      float lg = TEMPF * acc;
      __builtin_nontemporal_store(lg, lbase + (size_t)b * 6400000u);
      kk[b] = ((ull)ordf(lg) << 32) | (ull)(0xFFFFFFFFu - (unsigned)n);
    }
  } else {
#pragma unroll
    for (int b = 0; b < 16; ++b) kk[b] = 0ull;
  }
  const int w = tid >> 6;
#pragma unroll
  for (int b = 0; b < 16; ++b) {
    ull k = kk[b];
#pragma unroll
    for (int o = 32; o > 0; o >>= 1) {
      ull other = __shfl_xor(k, o, 64);
      k = k > other ? k : other;
    }
    if ((tid & 63) == 0) bw[w][b] = k;
  }
  __syncthreads();
  if (tid < 16) {
    ull m = bw[0][tid];
    m = bw[1][tid] > m ? bw[1][tid] : m;
    m = bw[2][tid] > m ? bw[2][tid] : m;
    m = bw[3][tid] > m ? bw[3][tid] : m;
    slots[(size_t)tid * 256 + bid] = m;
  }
}

// ---------------- launch ----------------

extern "C" void kernel_launch(void* const* d_in, const int* in_sizes, int n_in,
                              void* d_out, int out_size, void* d_ws, size_t ws_size,
                              hipStream_t stream) {
  const int* pred = (const int*)d_in[0];
  const int* lens = (const int*)d_in[1];
  const float* nnf = (const float*)d_in[2];
  const int* fid = (const int*)d_in[3];
  const int* ei = (const int*)d_in[4];
  const float* ea = (const float*)d_in[5];
  const int* tei = (const int*)d_in[6];
  const float* tw = (const float*)d_in[7];
  const float* femb = (const float*)d_in[8];
  const float* W_ne = (const float*)d_in[9];  const float* b_ne = (const float*)d_in[10];
  const float* W_e1 = (const float*)d_in[11]; const float* b_e1 = (const float*)d_in[12];
  const float* W_e2 = (const float*)d_in[13]; const float* b_e2 = (const float*)d_in[14];
  const float* g1W1 = (const float*)d_in[15]; const float* g1b1 = (const float*)d_in[16];
  const float* g1W2 = (const float*)d_in[17]; const float* g1b2 = (const float*)d_in[18];
  const float* g2W1 = (const float*)d_in[19]; const float* g2b1 = (const float*)d_in[20];
  const float* g2W2 = (const float*)d_in[21]; const float* g2b2 = (const float*)d_in[22];
  const float* W_t = (const float*)d_in[23];  const float* b_t = (const float*)d_in[24];
  const float* Wihf = (const float*)d_in[25]; const float* Whhf = (const float*)d_in[26];
  const float* bihf = (const float*)d_in[27]; const float* bhhf = (const float*)d_in[28];
  const float* Wihb = (const float*)d_in[29]; const float* Whhb = (const float*)d_in[30];
  const float* bihb = (const float*)d_in[31]; const float* bhhb = (const float*)d_in[32];
  const float* W_ep = (const float*)d_in[33]; const float* b_ep = (const float*)d_in[34];
  const float* Wihd = (const float*)d_in[35]; const float* Whhd = (const float*)d_in[36];
  const float* bihd = (const float*)d_in[37]; const float* bhhd = (const float*)d_in[38];
  const float* W_do = (const float*)d_in[39]; const float* b_do = (const float*)d_in[40];

  float* out = (float*)d_out;
  float* logits = out;
  float* HR = out + 102400000;  // second output

  // large scratch lives in the (not-yet-written) logits region
  float* Ee    = out + 0;
  float* H_a   = out + 12800000;
  float* H_b   = out + 16000000;
  float* agg   = out + 19200000;
  float* HRt   = out + 22400000;
  float* gi_f  = out + 25600000;
  float* gi_b  = out + 26000000;
  float* out_f = out + 26400000;
  float* out_b = out + 26600000;

  // decode-live scratch in d_ws (~1.1 MB)
  char* w8 = (char*)d_ws;
  ull* slots = (ull*)w8;                                   // 16*256*8 = 32 KB
  float* h_g = (float*)(w8 + 32768);                       // 4 KB
  float* z_g = (float*)(w8 + 32768 + 4096);                // 4 KB
  float* enc = (float*)(w8 + 32768 + 8192);                // 512 KB
  float* encT = enc + 131072;                              // 512 KB

  k_node_enc<<<12500, 256, 0, stream>>>(nnf, fid, femb, W_ne, b_ne, H_a);
  k_edge_proj<<<50000, 256, 0, stream>>>(ea, W_e1, b_e1, W_e2, b_e2, Ee);

  hipMemsetAsync(agg, 0, (size_t)N_NODES * 64 * 4, stream);
  k_gine_msg<<<50000, 256, 0, stream>>>(H_a, Ee, ei, agg);
  k_gine_mlp<<<1024, 256, 0, stream>>>(H_a, agg, g1W1, g1b1, g1W2, g1b2, H_b);

  hipMemsetAsync(agg, 0, (size_t)N_NODES * 64 * 4, stream);
  k_gine_msg<<<50000, 256, 0, stream>>>(H_b, Ee, ei, agg);
  k_gine_mlp<<<1024, 256, 0, stream>>>(H_b, agg, g2W1, g2b1, g2W2, g2b2, H_a);

  k_l2n<<<12500, 256, 0, stream>>>(H_a, HRt);

  hipMemsetAsync(agg, 0, (size_t)N_NODES * 64 * 4, stream);
  k_traj_msg<<<25000, 256, 0, stream>>>(HRt, tei, tw, agg);
  k_traj_mlp<<<12500, 256, 0, stream>>>(HRt, agg, W_t, b_t, HR);

  k_gi<<<2048, 192, 0, stream>>>(pred, lens, HR, Wihf, bihf, Wihb, bihb, gi_f, gi_b);
  k_gru<<<32, 192, 0, stream>>>(gi_f, gi_b, Whhf, bhhf, Whhb, bhhb, lens, out_f, out_b);
  k_encout<<<2048, 64, 0, stream>>>(out_f, out_b, W_ep, b_ep, enc, encT);
  k_encmean<<<1, 1024, 0, stream>>>(enc, lens, h_g);

  for (int t = 0; t < 128; ++t) {
    k_dec_a<<<16, 192, 0, stream>>>(HR, enc, encT, Wihd, Whhd, bihd, bhhd, W_do, b_do,
                                    lens, h_g, z_g, slots, t);
    k_dec_b<<<196, 256, 0, stream>>>(HR, z_g, logits, slots, t);
  }
}